// Round 8
// baseline (70.330 us; speedup 1.0000x reference)
//
#include <hip/hip_runtime.h>
#include <cstdint>
#include <cstddef>

#define F_DIM 39
#define E_DIM 32
#define B_DIM 16384
#define ROWSTRIDE 1248              // 39*32 floats per b row
#define EPS_BN 1e-5f
#define EPS_G 1e-10f

typedef _Float16 f16x8 __attribute__((ext_vector_type(8)));
typedef float f32x16 __attribute__((ext_vector_type(16)));
union H8 { _Float16 h[8]; f16x8 v; uint32_t u[4]; };

// workspace (float units), all fully overwritten each launch:
//   [0,      319488) : qpart[f*32+chunk][256]  ({Sy(128), Sy2(128)} per block)
//   [319488, 339456) : Whp[f][16][32] packed f16-hi pairs (uint32)
//   [339456, 359424) : Wlp[f][16][32] packed f16-lo pairs (uint32)
//   [359424, 360672) : bias[f][e]

// ---- pass 1: per-(f,chunk) Sy, Sy2 of candidate outputs, via MFMA Y-tiles ----
#define S_CHUNKS 32
#define S_RPB 512                    // rows/block; 128/wave; 4 tiles of 32

__global__ __launch_bounds__(256) void k_stats(const float* __restrict__ emb,
    const float* __restrict__ w4, const float* __restrict__ w8,
    const float* __restrict__ w16, const float* __restrict__ w32,
    float* __restrict__ qpart) {
    const int f = blockIdx.y;
    const int chunk = blockIdx.x;
    const int tid = threadIdx.x;
    const int wave = tid >> 6;
    const int l = tid & 63;
    const int g = l >> 5;
    const int c = l & 31;            // column: m-row for A, n (=e) for B/D

    // 5 non-zero B-fragments: idx -> (cc,kq): 0:(0,0) 1:(1,0) 2:(2,0) 3:(3,0) 4:(3,1)
    // k-slot p of half g holds k = 16*kq + 8*g + p (HW-validated rounds 2-5).
    H8 wf[5];
    {
        const float* wt[4] = {w4, w8, w16, w32};
#pragma unroll
        for (int idx = 0; idx < 5; ++idx) {
            const int cc = (idx < 4) ? idx : 3;
            const int kq = (idx < 4) ? 0 : 1;
            const int d = 4 << cc;
            const float* w = wt[cc] + (size_t)f * d * E_DIM;
#pragma unroll
            for (int p = 0; p < 8; ++p) {
                const int k = 16 * kq + 8 * g + p;
                wf[idx].h[p] = (k < d) ? (_Float16)w[k * E_DIM + c] : (_Float16)0.f;
            }
        }
    }

    float ysum[4] = {0.f, 0.f, 0.f, 0.f};
    float y2s[4] = {0.f, 0.f, 0.f, 0.f};
    const float* prow = emb + (size_t)(chunk * S_RPB + wave * 128 + c) * ROWSTRIDE + f * E_DIM;

#pragma unroll
    for (int t = 0; t < 4; ++t) {
        const float4* pa = reinterpret_cast<const float4*>(prow);
        const float4 v0 = pa[2 * g], v1 = pa[2 * g + 1];
        const float4 v2 = pa[4 + 2 * g], v3 = pa[4 + 2 * g + 1];
        H8 a0, a1;
        a0.h[0] = (_Float16)v0.x; a0.h[1] = (_Float16)v0.y;
        a0.h[2] = (_Float16)v0.z; a0.h[3] = (_Float16)v0.w;
        a0.h[4] = (_Float16)v1.x; a0.h[5] = (_Float16)v1.y;
        a0.h[6] = (_Float16)v1.z; a0.h[7] = (_Float16)v1.w;
        a1.h[0] = (_Float16)v2.x; a1.h[1] = (_Float16)v2.y;
        a1.h[2] = (_Float16)v2.z; a1.h[3] = (_Float16)v2.w;
        a1.h[4] = (_Float16)v3.x; a1.h[5] = (_Float16)v3.y;
        a1.h[6] = (_Float16)v3.z; a1.h[7] = (_Float16)v3.w;

#pragma unroll
        for (int cc = 0; cc < 4; ++cc) {
            f32x16 acc;
#pragma unroll
            for (int i = 0; i < 16; ++i) acc[i] = 0.f;
            acc = __builtin_amdgcn_mfma_f32_32x32x16_f16(a0.v, wf[cc].v, acc, 0, 0, 0);
            if (cc == 3)
                acc = __builtin_amdgcn_mfma_f32_32x32x16_f16(a1.v, wf[4].v, acc, 0, 0, 0);
            // column sums only: D col = c for this lane; row mapping irrelevant
#pragma unroll
            for (int r = 0; r < 16; ++r) {
                ysum[cc] += acc[r];
                y2s[cc] = fmaf(acc[r], acc[r], y2s[cc]);
            }
        }
        prow += (size_t)32 * ROWSTRIDE;
    }

#pragma unroll
    for (int cc = 0; cc < 4; ++cc) {
        ysum[cc] += __shfl_xor(ysum[cc], 32, 64);
        y2s[cc] += __shfl_xor(y2s[cc], 32, 64);
    }
    __shared__ float ldsY[4][128];
    __shared__ float ldsQ[4][128];
    if (l < 32) {
#pragma unroll
        for (int cc = 0; cc < 4; ++cc) {
            ldsY[wave][cc * 32 + c] = ysum[cc];
            ldsQ[wave][cc * 32 + c] = y2s[cc];
        }
    }
    __syncthreads();
    if (tid < 128) {
        float* qp = qpart + (size_t)(f * S_CHUNKS + chunk) * 256;
        qp[tid] = ldsY[0][tid] + ldsY[1][tid] + ldsY[2][tid] + ldsY[3][tid];
        qp[128 + tid] = ldsQ[0][tid] + ldsQ[1][tid] + ldsQ[2][tid] + ldsQ[3][tid];
    }
}

// ---- glue (merged): full qpart sum -> BN stats -> gates -> Weff/bias, per f ----
#define NUNITS (F_DIM * S_CHUNKS)    // 1248

__global__ __launch_bounds__(256) void k_build(
    const float* __restrict__ qpart,
    const float* __restrict__ gate, const float* __restrict__ noise,
    const float* __restrict__ w4, const float* __restrict__ w8,
    const float* __restrict__ w16, const float* __restrict__ w32,
    uint32_t* __restrict__ Whp, uint32_t* __restrict__ Wlp,
    float* __restrict__ biasb) {
    const int f = blockIdx.x;
    const int tid = threadIdx.x;
    __shared__ float ldsT[256];
    __shared__ float inv_s[4][32];
    __shared__ float mu_s[4][32];
    __shared__ float gate_s[4];

    {
        float ss[8];
#pragma unroll
        for (int i = 0; i < 8; ++i) ss[i] = 0.f;
        const float* qp = qpart + tid;
        for (int u0 = 0; u0 < NUNITS; u0 += 8) {
#pragma unroll
            for (int i = 0; i < 8; ++i)
                ss[i] += qp[(size_t)(u0 + i) * 256];
        }
        ldsT[tid] = ((ss[0] + ss[1]) + (ss[2] + ss[3])) +
                    ((ss[4] + ss[5]) + (ss[6] + ss[7]));
    }
    if (tid == 0) {
        float lg[4], mx = -1e30f;
#pragma unroll
        for (int cc = 0; cc < 4; ++cc) {
            const float u = noise[f * 4 + cc];
            const float gg = -logf(-logf(u + EPS_G) + EPS_G);
            lg[cc] = gate[f * 4 + cc] + gg;
            mx = fmaxf(mx, lg[cc]);
        }
        float se = 0.f;
#pragma unroll
        for (int cc = 0; cc < 4; ++cc) { lg[cc] = expf(lg[cc] - mx); se += lg[cc]; }
#pragma unroll
        for (int cc = 0; cc < 4; ++cc) gate_s[cc] = 0.25f * lg[cc] / se;
    }
    __syncthreads();
    if (tid < 128) {
        const int cc = tid >> 5, e = tid & 31;
        const float invBF = 1.0f / ((float)B_DIM * (float)F_DIM);
        const float mu = ldsT[tid] * invBF;
        const float ey2 = ldsT[128 + tid] * invBF;
        inv_s[cc][e] = rsqrtf(ey2 - mu * mu + EPS_BN);
        mu_s[cc][e] = mu;
    }
    __syncthreads();

    // Weff[f][i][e] packed as (i even, i odd) f16 pairs, split hi/lo
    for (int idx = tid; idx < 512; idx += 256) {
        const int kp = idx >> 5;
        const int e = idx & 31;
        const int i0 = kp * 2;
        float w0 = 0.f, w1 = 0.f;
#pragma unroll
        for (int cc = 0; cc < 4; ++cc) {
            const int d = 4 << cc;
            if (i0 < d) {
                const float* w = (cc == 0) ? w4 : (cc == 1) ? w8 : (cc == 2) ? w16 : w32;
                const float gi = gate_s[cc] * inv_s[cc][e];
                const size_t base = ((size_t)f * d + i0) * E_DIM + e;
                w0 = fmaf(gi, w[base], w0);
                w1 = fmaf(gi, w[base + E_DIM], w1);
            }
        }
        union { _Float16 h[2]; uint32_t uu; } ph, pl;
        const _Float16 h0 = (_Float16)w0, h1 = (_Float16)w1;
        ph.h[0] = h0; ph.h[1] = h1;
        pl.h[0] = (_Float16)(w0 - (float)h0);
        pl.h[1] = (_Float16)(w1 - (float)h1);
        Whp[f * 512 + idx] = ph.uu;
        Wlp[f * 512 + idx] = pl.uu;
    }
    if (tid < E_DIM) {
        float a = 0.f;
#pragma unroll
        for (int cc = 0; cc < 4; ++cc)
            a = fmaf(gate_s[cc], inv_s[cc][tid] * mu_s[cc][tid], a);
        biasb[f * E_DIM + tid] = a;
    }
}

// ---- pass 2: Out_f = X_f * Weff_f - bias via MFMA (f16 split) ----
#define A_CHUNKS 64
#define A_RPB (B_DIM / A_CHUNKS)     // 256 rows/block; 64/wave = 2 tiles of 32

__global__ __launch_bounds__(256) void k_apply(const float* __restrict__ emb,
                                               const uint32_t* __restrict__ Whp,
                                               const uint32_t* __restrict__ Wlp,
                                               const float* __restrict__ biasb,
                                               float* __restrict__ out) {
    const int f = blockIdx.y;
    const int tid = threadIdx.x;
    const int wave = tid >> 6;
    const int l = tid & 63;
    const int g = l >> 5;
    const int c = l & 31;

    H8 wh[2], wl[2];
#pragma unroll
    for (int q = 0; q < 2; ++q)
#pragma unroll
        for (int pp = 0; pp < 4; ++pp) {
            const int kp = 8 * q + 4 * g + pp;
            wh[q].u[pp] = Whp[f * 512 + kp * 32 + c];
            wl[q].u[pp] = Wlp[f * 512 + kp * 32 + c];
        }
    const float be = biasb[f * 32 + c];

    const int wbase = blockIdx.x * A_RPB + wave * (A_RPB / 4);
#pragma unroll
    for (int t = 0; t < (A_RPB / 4) / 32; ++t) {
        const int b0 = wbase + t * 32;
        const float4* pa = reinterpret_cast<const float4*>(
            emb + (size_t)(b0 + c) * ROWSTRIDE + f * E_DIM + 8 * g);
        f32x16 acc;
#pragma unroll
        for (int i = 0; i < 16; ++i) acc[i] = 0.f;
#pragma unroll
        for (int q = 0; q < 2; ++q) {
            const float4 v0 = pa[4 * q];
            const float4 v1 = pa[4 * q + 1];
            const float x[8] = {v0.x, v0.y, v0.z, v0.w, v1.x, v1.y, v1.z, v1.w};
            H8 ah, al;
#pragma unroll
            for (int e = 0; e < 8; ++e) {
                const _Float16 hh = (_Float16)x[e];
                ah.h[e] = hh;
                al.h[e] = (_Float16)(x[e] - (float)hh);
            }
            acc = __builtin_amdgcn_mfma_f32_32x32x16_f16(ah.v, wh[q].v, acc, 0, 0, 0);
            acc = __builtin_amdgcn_mfma_f32_32x32x16_f16(ah.v, wl[q].v, acc, 0, 0, 0);
            acc = __builtin_amdgcn_mfma_f32_32x32x16_f16(al.v, wh[q].v, acc, 0, 0, 0);
        }
        float* po = out + (size_t)b0 * ROWSTRIDE + f * E_DIM + c;
#pragma unroll
        for (int r = 0; r < 16; ++r) {
            const int mrow = (r & 3) + 8 * (r >> 2) + 4 * g;
            __builtin_nontemporal_store(acc[r] - be, po + (size_t)mrow * ROWSTRIDE);
        }
    }
}

extern "C" void kernel_launch(void* const* d_in, const int* in_sizes, int n_in,
                              void* d_out, int out_size, void* d_ws, size_t ws_size,
                              hipStream_t stream) {
    const float* emb   = (const float*)d_in[0];
    const float* w4    = (const float*)d_in[1];
    const float* w8    = (const float*)d_in[2];
    const float* w16   = (const float*)d_in[3];
    const float* w32   = (const float*)d_in[4];
    const float* gate  = (const float*)d_in[5];
    const float* noise = (const float*)d_in[6];
    float* out = (float*)d_out;

    float* ws     = (float*)d_ws;
    float* qpart  = ws;                           // 1248*256
    uint32_t* Whp = (uint32_t*)(ws + 319488);     // 39*512
    uint32_t* Wlp = (uint32_t*)(ws + 339456);     // 39*512
    float* biasb  = ws + 359424;                  // 39*32

    k_stats<<<dim3(S_CHUNKS, F_DIM), 256, 0, stream>>>(emb, w4, w8, w16, w32, qpart);
    k_build<<<F_DIM, 256, 0, stream>>>(qpart, gate, noise, w4, w8, w16, w32, Whp, Wlp, biasb);
    k_apply<<<dim3(A_CHUNKS, F_DIM), 256, 0, stream>>>(emb, Whp, Wlp, biasb, out);
}

// Round 9
// 63.976 us; speedup vs baseline: 1.0993x; 1.0993x over previous
//
#include <hip/hip_runtime.h>
#include <cstdint>
#include <cstddef>

#define F_DIM 39
#define E_DIM 32
#define B_DIM 16384
#define ROWSTRIDE 1248              // 39*32 floats per b row
#define EPS_BN 1e-5f
#define EPS_G 1e-10f

typedef _Float16 f16x8 __attribute__((ext_vector_type(8)));
typedef float f32x16 __attribute__((ext_vector_type(16)));
union H8 { _Float16 h[8]; f16x8 v; uint32_t u[4]; };

// workspace (float units), all fully overwritten each launch:
//   [0,      319488) : qpart[f*32+chunk][256]  ({Sy(128), Sy2(128)} per block)
//   [319488, 339456) : Whp[f][16][32] packed f16-hi pairs (uint32)
//   [339456, 359424) : Wlp[f][16][32] packed f16-lo pairs (uint32)
//   [359424, 360672) : bias[f][e]

// ---- pass 1: per-(f,chunk) Sy, Sy2 of candidate outputs, via MFMA Y-tiles ----
#define S_CHUNKS 32
#define S_RPB 512                    // rows/block; 128/wave; 4 tiles of 32

__global__ __launch_bounds__(256) void k_stats(const float* __restrict__ emb,
    const float* __restrict__ w4, const float* __restrict__ w8,
    const float* __restrict__ w16, const float* __restrict__ w32,
    float* __restrict__ qpart) {
    const int f = blockIdx.y;
    const int chunk = blockIdx.x;
    const int tid = threadIdx.x;
    const int wave = tid >> 6;
    const int l = tid & 63;
    const int g = l >> 5;
    const int c = l & 31;            // column: m-row for A, n (=e) for B/D

    // 5 non-zero B-fragments: idx -> (cc,kq): 0:(0,0) 1:(1,0) 2:(2,0) 3:(3,0) 4:(3,1)
    // k-slot p of half g holds k = 16*kq + 8*g + p (HW-validated rounds 2-5).
    H8 wf[5];
    {
        const float* wt[4] = {w4, w8, w16, w32};
#pragma unroll
        for (int idx = 0; idx < 5; ++idx) {
            const int cc = (idx < 4) ? idx : 3;
            const int kq = (idx < 4) ? 0 : 1;
            const int d = 4 << cc;
            const float* w = wt[cc] + (size_t)f * d * E_DIM;
#pragma unroll
            for (int p = 0; p < 8; ++p) {
                const int k = 16 * kq + 8 * g + p;
                wf[idx].h[p] = (k < d) ? (_Float16)w[k * E_DIM + c] : (_Float16)0.f;
            }
        }
    }

    float ysum[4] = {0.f, 0.f, 0.f, 0.f};
    float y2s[4] = {0.f, 0.f, 0.f, 0.f};
    const float* prow = emb + (size_t)(chunk * S_RPB + wave * 128 + c) * ROWSTRIDE + f * E_DIM;

#pragma unroll
    for (int t = 0; t < 4; ++t) {
        const float4* pa = reinterpret_cast<const float4*>(prow);
        const float4 v0 = pa[2 * g], v1 = pa[2 * g + 1];
        const float4 v2 = pa[4 + 2 * g], v3 = pa[4 + 2 * g + 1];
        H8 a0, a1;
        a0.h[0] = (_Float16)v0.x; a0.h[1] = (_Float16)v0.y;
        a0.h[2] = (_Float16)v0.z; a0.h[3] = (_Float16)v0.w;
        a0.h[4] = (_Float16)v1.x; a0.h[5] = (_Float16)v1.y;
        a0.h[6] = (_Float16)v1.z; a0.h[7] = (_Float16)v1.w;
        a1.h[0] = (_Float16)v2.x; a1.h[1] = (_Float16)v2.y;
        a1.h[2] = (_Float16)v2.z; a1.h[3] = (_Float16)v2.w;
        a1.h[4] = (_Float16)v3.x; a1.h[5] = (_Float16)v3.y;
        a1.h[6] = (_Float16)v3.z; a1.h[7] = (_Float16)v3.w;

#pragma unroll
        for (int cc = 0; cc < 4; ++cc) {
            f32x16 acc;
#pragma unroll
            for (int i = 0; i < 16; ++i) acc[i] = 0.f;
            acc = __builtin_amdgcn_mfma_f32_32x32x16_f16(a0.v, wf[cc].v, acc, 0, 0, 0);
            if (cc == 3)
                acc = __builtin_amdgcn_mfma_f32_32x32x16_f16(a1.v, wf[4].v, acc, 0, 0, 0);
            // column sums only: D col = c for this lane; row mapping irrelevant
#pragma unroll
            for (int r = 0; r < 16; ++r) {
                ysum[cc] += acc[r];
                y2s[cc] = fmaf(acc[r], acc[r], y2s[cc]);
            }
        }
        prow += (size_t)32 * ROWSTRIDE;
    }

#pragma unroll
    for (int cc = 0; cc < 4; ++cc) {
        ysum[cc] += __shfl_xor(ysum[cc], 32, 64);
        y2s[cc] += __shfl_xor(y2s[cc], 32, 64);
    }
    __shared__ float ldsY[4][128];
    __shared__ float ldsQ[4][128];
    if (l < 32) {
#pragma unroll
        for (int cc = 0; cc < 4; ++cc) {
            ldsY[wave][cc * 32 + c] = ysum[cc];
            ldsQ[wave][cc * 32 + c] = y2s[cc];
        }
    }
    __syncthreads();
    if (tid < 128) {
        float* qp = qpart + (size_t)(f * S_CHUNKS + chunk) * 256;
        qp[tid] = ldsY[0][tid] + ldsY[1][tid] + ldsY[2][tid] + ldsY[3][tid];
        qp[128 + tid] = ldsQ[0][tid] + ldsQ[1][tid] + ldsQ[2][tid] + ldsQ[3][tid];
    }
}

// ---- glue (merged, latency-proof): qpart sum -> BN stats -> gates -> Weff/bias ----
// 39 blocks x 1024 threads: 4 slices x 256 columns, 16-way ILP per thread
// (312 units/slice => ~20 rounds of 16 outstanding loads), LDS combine.
#define NUNITS (F_DIM * S_CHUNKS)    // 1248
#define SLICE (NUNITS / 4)           // 312

__global__ __launch_bounds__(1024) void k_build(
    const float* __restrict__ qpart,
    const float* __restrict__ gate, const float* __restrict__ noise,
    const float* __restrict__ w4, const float* __restrict__ w8,
    const float* __restrict__ w16, const float* __restrict__ w32,
    uint32_t* __restrict__ Whp, uint32_t* __restrict__ Wlp,
    float* __restrict__ biasb) {
    const int f = blockIdx.x;
    const int tid = threadIdx.x;
    const int j = tid & 255;         // column
    const int s = tid >> 8;          // slice 0..3
    __shared__ float ldsP[4][256];
    __shared__ float ldsT[256];
    __shared__ float inv_s[4][32];
    __shared__ float mu_s[4][32];
    __shared__ float gate_s[4];

    {
        float ss[16];
#pragma unroll
        for (int i = 0; i < 16; ++i) ss[i] = 0.f;
        const float* qp = qpart + (size_t)s * SLICE * 256 + j;
        int u0 = 0;
        for (; u0 + 16 <= SLICE; u0 += 16) {
#pragma unroll
            for (int i = 0; i < 16; ++i)
                ss[i] += qp[(size_t)(u0 + i) * 256];
        }
#pragma unroll
        for (int i = 0; i < 8; ++i)          // tail: 312 = 19*16 + 8
            ss[i] += qp[(size_t)(u0 + i) * 256];
        float t0 = ((ss[0] + ss[1]) + (ss[2] + ss[3])) +
                   ((ss[4] + ss[5]) + (ss[6] + ss[7]));
        float t1 = ((ss[8] + ss[9]) + (ss[10] + ss[11])) +
                   ((ss[12] + ss[13]) + (ss[14] + ss[15]));
        ldsP[s][j] = t0 + t1;
    }
    __syncthreads();
    if (tid < 256)
        ldsT[tid] = (ldsP[0][tid] + ldsP[1][tid]) + (ldsP[2][tid] + ldsP[3][tid]);
    if (tid == 0) {
        float lg[4], mx = -1e30f;
#pragma unroll
        for (int cc = 0; cc < 4; ++cc) {
            const float u = noise[f * 4 + cc];
            const float gg = -logf(-logf(u + EPS_G) + EPS_G);
            lg[cc] = gate[f * 4 + cc] + gg;
            mx = fmaxf(mx, lg[cc]);
        }
        float se = 0.f;
#pragma unroll
        for (int cc = 0; cc < 4; ++cc) { lg[cc] = expf(lg[cc] - mx); se += lg[cc]; }
#pragma unroll
        for (int cc = 0; cc < 4; ++cc) gate_s[cc] = 0.25f * lg[cc] / se;
    }
    __syncthreads();
    if (tid < 128) {
        const int cc = tid >> 5, e = tid & 31;
        const float invBF = 1.0f / ((float)B_DIM * (float)F_DIM);
        const float mu = ldsT[tid] * invBF;
        const float ey2 = ldsT[128 + tid] * invBF;
        inv_s[cc][e] = rsqrtf(ey2 - mu * mu + EPS_BN);
        mu_s[cc][e] = mu;
    }
    __syncthreads();

    // Weff[f][i][e] packed as (i even, i odd) f16 pairs, split hi/lo
    if (tid < 512) {
        const int idx = tid;
        const int kp = idx >> 5;
        const int e = idx & 31;
        const int i0 = kp * 2;
        float w0 = 0.f, w1 = 0.f;
#pragma unroll
        for (int cc = 0; cc < 4; ++cc) {
            const int d = 4 << cc;
            if (i0 < d) {
                const float* w = (cc == 0) ? w4 : (cc == 1) ? w8 : (cc == 2) ? w16 : w32;
                const float gi = gate_s[cc] * inv_s[cc][e];
                const size_t base = ((size_t)f * d + i0) * E_DIM + e;
                w0 = fmaf(gi, w[base], w0);
                w1 = fmaf(gi, w[base + E_DIM], w1);
            }
        }
        union { _Float16 h[2]; uint32_t uu; } ph, pl;
        const _Float16 h0 = (_Float16)w0, h1 = (_Float16)w1;
        ph.h[0] = h0; ph.h[1] = h1;
        pl.h[0] = (_Float16)(w0 - (float)h0);
        pl.h[1] = (_Float16)(w1 - (float)h1);
        Whp[f * 512 + idx] = ph.uu;
        Wlp[f * 512 + idx] = pl.uu;
    }
    if (tid < E_DIM) {
        float a = 0.f;
#pragma unroll
        for (int cc = 0; cc < 4; ++cc)
            a = fmaf(gate_s[cc], inv_s[cc][tid] * mu_s[cc][tid], a);
        biasb[f * E_DIM + tid] = a;
    }
}

// ---- pass 2: Out_f = X_f * Weff_f - bias via MFMA (f16 split) ----
#define A_CHUNKS 64
#define A_RPB (B_DIM / A_CHUNKS)     // 256 rows/block; 64/wave = 2 tiles of 32

__global__ __launch_bounds__(256) void k_apply(const float* __restrict__ emb,
                                               const uint32_t* __restrict__ Whp,
                                               const uint32_t* __restrict__ Wlp,
                                               const float* __restrict__ biasb,
                                               float* __restrict__ out) {
    const int f = blockIdx.y;
    const int tid = threadIdx.x;
    const int wave = tid >> 6;
    const int l = tid & 63;
    const int g = l >> 5;
    const int c = l & 31;

    H8 wh[2], wl[2];
#pragma unroll
    for (int q = 0; q < 2; ++q)
#pragma unroll
        for (int pp = 0; pp < 4; ++pp) {
            const int kp = 8 * q + 4 * g + pp;
            wh[q].u[pp] = Whp[f * 512 + kp * 32 + c];
            wl[q].u[pp] = Wlp[f * 512 + kp * 32 + c];
        }
    const float be = biasb[f * 32 + c];

    const int wbase = blockIdx.x * A_RPB + wave * (A_RPB / 4);
#pragma unroll
    for (int t = 0; t < (A_RPB / 4) / 32; ++t) {
        const int b0 = wbase + t * 32;
        const float4* pa = reinterpret_cast<const float4*>(
            emb + (size_t)(b0 + c) * ROWSTRIDE + f * E_DIM + 8 * g);
        f32x16 acc;
#pragma unroll
        for (int i = 0; i < 16; ++i) acc[i] = 0.f;
#pragma unroll
        for (int q = 0; q < 2; ++q) {
            const float4 v0 = pa[4 * q];
            const float4 v1 = pa[4 * q + 1];
            const float x[8] = {v0.x, v0.y, v0.z, v0.w, v1.x, v1.y, v1.z, v1.w};
            H8 ah, al;
#pragma unroll
            for (int e = 0; e < 8; ++e) {
                const _Float16 hh = (_Float16)x[e];
                ah.h[e] = hh;
                al.h[e] = (_Float16)(x[e] - (float)hh);
            }
            acc = __builtin_amdgcn_mfma_f32_32x32x16_f16(ah.v, wh[q].v, acc, 0, 0, 0);
            acc = __builtin_amdgcn_mfma_f32_32x32x16_f16(ah.v, wl[q].v, acc, 0, 0, 0);
            acc = __builtin_amdgcn_mfma_f32_32x32x16_f16(al.v, wh[q].v, acc, 0, 0, 0);
        }
        float* po = out + (size_t)b0 * ROWSTRIDE + f * E_DIM + c;
#pragma unroll
        for (int r = 0; r < 16; ++r) {
            const int mrow = (r & 3) + 8 * (r >> 2) + 4 * g;
            __builtin_nontemporal_store(acc[r] - be, po + (size_t)mrow * ROWSTRIDE);
        }
    }
}

extern "C" void kernel_launch(void* const* d_in, const int* in_sizes, int n_in,
                              void* d_out, int out_size, void* d_ws, size_t ws_size,
                              hipStream_t stream) {
    const float* emb   = (const float*)d_in[0];
    const float* w4    = (const float*)d_in[1];
    const float* w8    = (const float*)d_in[2];
    const float* w16   = (const float*)d_in[3];
    const float* w32   = (const float*)d_in[4];
    const float* gate  = (const float*)d_in[5];
    const float* noise = (const float*)d_in[6];
    float* out = (float*)d_out;

    float* ws     = (float*)d_ws;
    float* qpart  = ws;                           // 1248*256
    uint32_t* Whp = (uint32_t*)(ws + 319488);     // 39*512
    uint32_t* Wlp = (uint32_t*)(ws + 339456);     // 39*512
    float* biasb  = ws + 359424;                  // 39*32

    k_stats<<<dim3(S_CHUNKS, F_DIM), 256, 0, stream>>>(emb, w4, w8, w16, w32, qpart);
    k_build<<<F_DIM, 1024, 0, stream>>>(qpart, gate, noise, w4, w8, w16, w32, Whp, Wlp, biasb);
    k_apply<<<dim3(A_CHUNKS, F_DIM), 256, 0, stream>>>(emb, Whp, Wlp, biasb, out);
}

// Round 10
// 56.221 us; speedup vs baseline: 1.2510x; 1.1379x over previous
//
#include <hip/hip_runtime.h>
#include <cstdint>
#include <cstddef>

#define F_DIM 39
#define E_DIM 32
#define B_DIM 16384
#define ROWSTRIDE 1248              // 39*32 floats per b row
#define EPS_BN 1e-5f
#define EPS_G 1e-10f
#define NREP 8                      // m12 replica count (atomic spread)

typedef _Float16 f16x8 __attribute__((ext_vector_type(8)));
typedef float f32x16 __attribute__((ext_vector_type(16)));
union H8 { _Float16 h[8]; f16x8 v; uint32_t u[4]; };

// workspace (float units):
//   [0, 2048) : m12f[rep][256]  ({Sy(128), Sy2(128)} per replica) -- memset to 0
//               each launch, then atomically accumulated by k_stats.

// ---- pass 1: global Sy, Sy2 of candidate outputs via MFMA Y-tiles + atomics ----
#define S_CHUNKS 32
#define S_RPB 512                    // rows/block; 128/wave; 4 tiles of 32

__global__ __launch_bounds__(256) void k_stats(const float* __restrict__ emb,
    const float* __restrict__ w4, const float* __restrict__ w8,
    const float* __restrict__ w16, const float* __restrict__ w32,
    float* __restrict__ m12f) {
    const int f = blockIdx.y;
    const int chunk = blockIdx.x;
    const int tid = threadIdx.x;
    const int wave = tid >> 6;
    const int l = tid & 63;
    const int g = l >> 5;
    const int c = l & 31;            // column: m-row for A, n (=e) for B/D

    // 5 non-zero B-fragments: idx -> (cc,kq): 0:(0,0) 1:(1,0) 2:(2,0) 3:(3,0) 4:(3,1)
    // k-slot p of half g holds k = 16*kq + 8*g + p (HW-validated rounds 2-5, 8-9).
    H8 wf[5];
    {
        const float* wt[4] = {w4, w8, w16, w32};
#pragma unroll
        for (int idx = 0; idx < 5; ++idx) {
            const int cc = (idx < 4) ? idx : 3;
            const int kq = (idx < 4) ? 0 : 1;
            const int d = 4 << cc;
            const float* w = wt[cc] + (size_t)f * d * E_DIM;
#pragma unroll
            for (int p = 0; p < 8; ++p) {
                const int k = 16 * kq + 8 * g + p;
                wf[idx].h[p] = (k < d) ? (_Float16)w[k * E_DIM + c] : (_Float16)0.f;
            }
        }
    }

    float ysum[4] = {0.f, 0.f, 0.f, 0.f};
    float y2s[4] = {0.f, 0.f, 0.f, 0.f};
    const float* prow = emb + (size_t)(chunk * S_RPB + wave * 128 + c) * ROWSTRIDE + f * E_DIM;

#pragma unroll
    for (int t = 0; t < 4; ++t) {
        const float4* pa = reinterpret_cast<const float4*>(prow);
        const float4 v0 = pa[2 * g], v1 = pa[2 * g + 1];
        const float4 v2 = pa[4 + 2 * g], v3 = pa[4 + 2 * g + 1];
        H8 a0, a1;
        a0.h[0] = (_Float16)v0.x; a0.h[1] = (_Float16)v0.y;
        a0.h[2] = (_Float16)v0.z; a0.h[3] = (_Float16)v0.w;
        a0.h[4] = (_Float16)v1.x; a0.h[5] = (_Float16)v1.y;
        a0.h[6] = (_Float16)v1.z; a0.h[7] = (_Float16)v1.w;
        a1.h[0] = (_Float16)v2.x; a1.h[1] = (_Float16)v2.y;
        a1.h[2] = (_Float16)v2.z; a1.h[3] = (_Float16)v2.w;
        a1.h[4] = (_Float16)v3.x; a1.h[5] = (_Float16)v3.y;
        a1.h[6] = (_Float16)v3.z; a1.h[7] = (_Float16)v3.w;

#pragma unroll
        for (int cc = 0; cc < 4; ++cc) {
            f32x16 acc;
#pragma unroll
            for (int i = 0; i < 16; ++i) acc[i] = 0.f;
            acc = __builtin_amdgcn_mfma_f32_32x32x16_f16(a0.v, wf[cc].v, acc, 0, 0, 0);
            if (cc == 3)
                acc = __builtin_amdgcn_mfma_f32_32x32x16_f16(a1.v, wf[4].v, acc, 0, 0, 0);
            // column sums only: D col = c for this lane; row mapping irrelevant
#pragma unroll
            for (int r = 0; r < 16; ++r) {
                ysum[cc] += acc[r];
                y2s[cc] = fmaf(acc[r], acc[r], y2s[cc]);
            }
        }
        prow += (size_t)32 * ROWSTRIDE;
    }

#pragma unroll
    for (int cc = 0; cc < 4; ++cc) {
        ysum[cc] += __shfl_xor(ysum[cc], 32, 64);
        y2s[cc] += __shfl_xor(y2s[cc], 32, 64);
    }
    __shared__ float ldsY[4][128];
    __shared__ float ldsQ[4][128];
    if (l < 32) {
#pragma unroll
        for (int cc = 0; cc < 4; ++cc) {
            ldsY[wave][cc * 32 + c] = ysum[cc];
            ldsQ[wave][cc * 32 + c] = y2s[cc];
        }
    }
    __syncthreads();
    if (tid < 128) {
        const int rep = chunk & (NREP - 1);
        unsafeAtomicAdd(&m12f[rep * 256 + tid],
                        ldsY[0][tid] + ldsY[1][tid] + ldsY[2][tid] + ldsY[3][tid]);
        unsafeAtomicAdd(&m12f[rep * 256 + 128 + tid],
                        ldsQ[0][tid] + ldsQ[1][tid] + ldsQ[2][tid] + ldsQ[3][tid]);
    }
}

// ---- pass 2 (fused): replica-sum -> BN stats -> gates -> LDS Weff -> apply ----
#define A_CHUNKS 64
#define A_RPB (B_DIM / A_CHUNKS)     // 256 rows/block; 64/wave = 2 tiles of 32

__global__ __launch_bounds__(256) void k_apply(const float* __restrict__ emb,
    const float* __restrict__ m12f,
    const float* __restrict__ gate, const float* __restrict__ noise,
    const float* __restrict__ w4, const float* __restrict__ w8,
    const float* __restrict__ w16, const float* __restrict__ w32,
    float* __restrict__ out) {
    const int f = blockIdx.y;
    const int tid = threadIdx.x;
    const int wave = tid >> 6;
    const int l = tid & 63;
    const int g = l >> 5;
    const int c = l & 31;

    __shared__ float ldsT[256];
    __shared__ float inv_s[4][32];
    __shared__ float mu_s[4][32];
    __shared__ float gate_s[4];
    __shared__ uint32_t ldsWhp[512];
    __shared__ uint32_t ldsWlp[512];
    __shared__ float ldsBias[32];

    // ---- build prologue ----
    {
        float s0 = 0.f, s1 = 0.f, s2 = 0.f, s3 = 0.f;
#pragma unroll
        for (int r = 0; r < NREP; r += 4) {
            s0 += m12f[(r + 0) * 256 + tid];
            s1 += m12f[(r + 1) * 256 + tid];
            s2 += m12f[(r + 2) * 256 + tid];
            s3 += m12f[(r + 3) * 256 + tid];
        }
        ldsT[tid] = (s0 + s1) + (s2 + s3);
    }
    if (tid == 0) {
        float lg[4], mx = -1e30f;
#pragma unroll
        for (int cc = 0; cc < 4; ++cc) {
            const float u = noise[f * 4 + cc];
            const float gg = -logf(-logf(u + EPS_G) + EPS_G);
            lg[cc] = gate[f * 4 + cc] + gg;
            mx = fmaxf(mx, lg[cc]);
        }
        float se = 0.f;
#pragma unroll
        for (int cc = 0; cc < 4; ++cc) { lg[cc] = expf(lg[cc] - mx); se += lg[cc]; }
#pragma unroll
        for (int cc = 0; cc < 4; ++cc) gate_s[cc] = 0.25f * lg[cc] / se;
    }
    __syncthreads();
    if (tid < 128) {
        const int cc = tid >> 5, e = tid & 31;
        const float invBF = 1.0f / ((float)B_DIM * (float)F_DIM);
        const float mu = ldsT[tid] * invBF;
        const float ey2 = ldsT[128 + tid] * invBF;
        inv_s[cc][e] = rsqrtf(ey2 - mu * mu + EPS_BN);
        mu_s[cc][e] = mu;
    }
    __syncthreads();

    for (int idx = tid; idx < 512; idx += 256) {
        const int kp = idx >> 5;
        const int e = idx & 31;
        const int i0 = kp * 2;
        float w0 = 0.f, w1 = 0.f;
#pragma unroll
        for (int cc = 0; cc < 4; ++cc) {
            const int d = 4 << cc;
            if (i0 < d) {
                const float* w = (cc == 0) ? w4 : (cc == 1) ? w8 : (cc == 2) ? w16 : w32;
                const float gi = gate_s[cc] * inv_s[cc][e];
                const size_t base = ((size_t)f * d + i0) * E_DIM + e;
                w0 = fmaf(gi, w[base], w0);
                w1 = fmaf(gi, w[base + E_DIM], w1);
            }
        }
        union { _Float16 h[2]; uint32_t uu; } ph, pl;
        const _Float16 h0 = (_Float16)w0, h1 = (_Float16)w1;
        ph.h[0] = h0; ph.h[1] = h1;
        pl.h[0] = (_Float16)(w0 - (float)h0);
        pl.h[1] = (_Float16)(w1 - (float)h1);
        ldsWhp[idx] = ph.uu;
        ldsWlp[idx] = pl.uu;
    }
    if (tid < E_DIM) {
        float a = 0.f;
#pragma unroll
        for (int cc = 0; cc < 4; ++cc)
            a = fmaf(gate_s[cc], inv_s[cc][tid] * mu_s[cc][tid], a);
        ldsBias[tid] = a;
    }
    __syncthreads();

    // ---- apply main loop ----
    H8 wh[2], wl[2];
#pragma unroll
    for (int q = 0; q < 2; ++q)
#pragma unroll
        for (int pp = 0; pp < 4; ++pp) {
            const int kp = 8 * q + 4 * g + pp;
            wh[q].u[pp] = ldsWhp[kp * 32 + c];
            wl[q].u[pp] = ldsWlp[kp * 32 + c];
        }
    const float be = ldsBias[c];

    const int wbase = blockIdx.x * A_RPB + wave * (A_RPB / 4);
#pragma unroll
    for (int t = 0; t < (A_RPB / 4) / 32; ++t) {
        const int b0 = wbase + t * 32;
        const float4* pa = reinterpret_cast<const float4*>(
            emb + (size_t)(b0 + c) * ROWSTRIDE + f * E_DIM + 8 * g);
        f32x16 acc;
#pragma unroll
        for (int i = 0; i < 16; ++i) acc[i] = 0.f;
#pragma unroll
        for (int q = 0; q < 2; ++q) {
            const float4 v0 = pa[4 * q];
            const float4 v1 = pa[4 * q + 1];
            const float x[8] = {v0.x, v0.y, v0.z, v0.w, v1.x, v1.y, v1.z, v1.w};
            H8 ah, al;
#pragma unroll
            for (int e = 0; e < 8; ++e) {
                const _Float16 hh = (_Float16)x[e];
                ah.h[e] = hh;
                al.h[e] = (_Float16)(x[e] - (float)hh);
            }
            acc = __builtin_amdgcn_mfma_f32_32x32x16_f16(ah.v, wh[q].v, acc, 0, 0, 0);
            acc = __builtin_amdgcn_mfma_f32_32x32x16_f16(ah.v, wl[q].v, acc, 0, 0, 0);
            acc = __builtin_amdgcn_mfma_f32_32x32x16_f16(al.v, wh[q].v, acc, 0, 0, 0);
        }
        float* po = out + (size_t)b0 * ROWSTRIDE + f * E_DIM + c;
#pragma unroll
        for (int r = 0; r < 16; ++r) {
            const int mrow = (r & 3) + 8 * (r >> 2) + 4 * g;
            __builtin_nontemporal_store(acc[r] - be, po + (size_t)mrow * ROWSTRIDE);
        }
    }
}

extern "C" void kernel_launch(void* const* d_in, const int* in_sizes, int n_in,
                              void* d_out, int out_size, void* d_ws, size_t ws_size,
                              hipStream_t stream) {
    const float* emb   = (const float*)d_in[0];
    const float* w4    = (const float*)d_in[1];
    const float* w8    = (const float*)d_in[2];
    const float* w16   = (const float*)d_in[3];
    const float* w32   = (const float*)d_in[4];
    const float* gate  = (const float*)d_in[5];
    const float* noise = (const float*)d_in[6];
    float* out = (float*)d_out;

    float* m12f = (float*)d_ws;       // NREP*256 floats

    hipMemsetAsync(m12f, 0, NREP * 256 * sizeof(float), stream);
    k_stats<<<dim3(S_CHUNKS, F_DIM), 256, 0, stream>>>(emb, w4, w8, w16, w32, m12f);
    k_apply<<<dim3(A_CHUNKS, F_DIM), 256, 0, stream>>>(emb, m12f, gate, noise,
                                                       w4, w8, w16, w32, out);
}

// Round 11
// 55.500 us; speedup vs baseline: 1.2672x; 1.0130x over previous
//
#include <hip/hip_runtime.h>
#include <cstdint>
#include <cstddef>

#define F_DIM 39
#define E_DIM 32
#define B_DIM 16384
#define ROWSTRIDE 1248              // 39*32 floats per b row
#define EPS_BN 1e-5f
#define EPS_G 1e-10f
#define NREP 8                      // m12 replica count (atomic spread)

typedef _Float16 f16x8 __attribute__((ext_vector_type(8)));
typedef float f32x16 __attribute__((ext_vector_type(16)));
union H8 { _Float16 h[8]; f16x8 v; uint32_t u[4]; };

// workspace (float units):
//   [0, 2048) : m12f[rep][256]  ({Sy(128), Sy2(128)} per replica) -- memset to 0
//               each launch, then atomically accumulated by k_stats.

// ---- pass 1: global Sy, Sy2 of candidate outputs via MFMA Y-tiles + atomics ----
#define S_CHUNKS 32
#define S_RPB 512                    // rows/block; 128/wave; 4 tiles of 32

__global__ __launch_bounds__(256) void k_stats(const float* __restrict__ emb,
    const float* __restrict__ w4, const float* __restrict__ w8,
    const float* __restrict__ w16, const float* __restrict__ w32,
    float* __restrict__ m12f) {
    const int f = blockIdx.y;
    const int chunk = blockIdx.x;
    const int tid = threadIdx.x;
    const int wave = tid >> 6;
    const int l = tid & 63;
    const int g = l >> 5;
    const int c = l & 31;            // column: m-row for A, n (=e) for B/D

    // 5 non-zero B-fragments: idx -> (cc,kq): 0:(0,0) 1:(1,0) 2:(2,0) 3:(3,0) 4:(3,1)
    // k-slot p of half g holds k = 16*kq + 8*g + p (HW-validated rounds 2-5, 8-10).
    H8 wf[5];
    {
        const float* wt[4] = {w4, w8, w16, w32};
#pragma unroll
        for (int idx = 0; idx < 5; ++idx) {
            const int cc = (idx < 4) ? idx : 3;
            const int kq = (idx < 4) ? 0 : 1;
            const int d = 4 << cc;
            const float* w = wt[cc] + (size_t)f * d * E_DIM;
#pragma unroll
            for (int p = 0; p < 8; ++p) {
                const int k = 16 * kq + 8 * g + p;
                wf[idx].h[p] = (k < d) ? (_Float16)w[k * E_DIM + c] : (_Float16)0.f;
            }
        }
    }

    float ysum[4] = {0.f, 0.f, 0.f, 0.f};
    float y2s[4] = {0.f, 0.f, 0.f, 0.f};
    const float* prow = emb + (size_t)(chunk * S_RPB + wave * 128 + c) * ROWSTRIDE + f * E_DIM;

#pragma unroll
    for (int t = 0; t < 4; ++t) {
        const float4* pa = reinterpret_cast<const float4*>(prow);
        const float4 v0 = pa[2 * g], v1 = pa[2 * g + 1];
        const float4 v2 = pa[4 + 2 * g], v3 = pa[4 + 2 * g + 1];
        H8 a0, a1;
        a0.h[0] = (_Float16)v0.x; a0.h[1] = (_Float16)v0.y;
        a0.h[2] = (_Float16)v0.z; a0.h[3] = (_Float16)v0.w;
        a0.h[4] = (_Float16)v1.x; a0.h[5] = (_Float16)v1.y;
        a0.h[6] = (_Float16)v1.z; a0.h[7] = (_Float16)v1.w;
        a1.h[0] = (_Float16)v2.x; a1.h[1] = (_Float16)v2.y;
        a1.h[2] = (_Float16)v2.z; a1.h[3] = (_Float16)v2.w;
        a1.h[4] = (_Float16)v3.x; a1.h[5] = (_Float16)v3.y;
        a1.h[6] = (_Float16)v3.z; a1.h[7] = (_Float16)v3.w;

#pragma unroll
        for (int cc = 0; cc < 4; ++cc) {
            f32x16 acc;
#pragma unroll
            for (int i = 0; i < 16; ++i) acc[i] = 0.f;
            acc = __builtin_amdgcn_mfma_f32_32x32x16_f16(a0.v, wf[cc].v, acc, 0, 0, 0);
            if (cc == 3)
                acc = __builtin_amdgcn_mfma_f32_32x32x16_f16(a1.v, wf[4].v, acc, 0, 0, 0);
            // column sums only: D col = c for this lane; row mapping irrelevant
#pragma unroll
            for (int r = 0; r < 16; ++r) {
                ysum[cc] += acc[r];
                y2s[cc] = fmaf(acc[r], acc[r], y2s[cc]);
            }
        }
        prow += (size_t)32 * ROWSTRIDE;
    }

#pragma unroll
    for (int cc = 0; cc < 4; ++cc) {
        ysum[cc] += __shfl_xor(ysum[cc], 32, 64);
        y2s[cc] += __shfl_xor(y2s[cc], 32, 64);
    }
    __shared__ float ldsY[4][128];
    __shared__ float ldsQ[4][128];
    if (l < 32) {
#pragma unroll
        for (int cc = 0; cc < 4; ++cc) {
            ldsY[wave][cc * 32 + c] = ysum[cc];
            ldsQ[wave][cc * 32 + c] = y2s[cc];
        }
    }
    __syncthreads();
    if (tid < 128) {
        const int rep = chunk & (NREP - 1);
        unsafeAtomicAdd(&m12f[rep * 256 + tid],
                        ldsY[0][tid] + ldsY[1][tid] + ldsY[2][tid] + ldsY[3][tid]);
        unsafeAtomicAdd(&m12f[rep * 256 + 128 + tid],
                        ldsQ[0][tid] + ldsQ[1][tid] + ldsQ[2][tid] + ldsQ[3][tid]);
    }
}

// ---- pass 2 (fused): replica-sum -> BN stats -> gates -> LDS Weff -> apply ----
#define A_CHUNKS 32
#define A_RPB (B_DIM / A_CHUNKS)     // 512 rows/block; 128/wave = 4 tiles of 32

__global__ __launch_bounds__(256) void k_apply(const float* __restrict__ emb,
    const float* __restrict__ m12f,
    const float* __restrict__ gate, const float* __restrict__ noise,
    const float* __restrict__ w4, const float* __restrict__ w8,
    const float* __restrict__ w16, const float* __restrict__ w32,
    float* __restrict__ out) {
    const int f = blockIdx.y;
    const int tid = threadIdx.x;
    const int wave = tid >> 6;
    const int l = tid & 63;
    const int g = l >> 5;
    const int c = l & 31;

    __shared__ float ldsT[256];
    __shared__ float lg4[4];
    __shared__ float inv_s[4][32];
    __shared__ float mu_s[4][32];
    __shared__ float gate_s[4];
    __shared__ uint32_t ldsWhp[512];
    __shared__ uint32_t ldsWlp[512];
    __shared__ float ldsBias[32];

    // ---- build prologue ----
    {
        float s0 = 0.f, s1 = 0.f, s2 = 0.f, s3 = 0.f;
#pragma unroll
        for (int r = 0; r < NREP; r += 4) {
            s0 += m12f[(r + 0) * 256 + tid];
            s1 += m12f[(r + 1) * 256 + tid];
            s2 += m12f[(r + 2) * 256 + tid];
            s3 += m12f[(r + 3) * 256 + tid];
        }
        ldsT[tid] = (s0 + s1) + (s2 + s3);
    }
    if (tid < 4) {
        // per-lane gumbel logit (parallel log/log/exp)
        const float u = noise[f * 4 + tid];
        const float gg = -logf(-logf(u + EPS_G) + EPS_G);
        lg4[tid] = gate[f * 4 + tid] + gg;
    }
    __syncthreads();
    if (tid < 4) {
        const float mx = fmaxf(fmaxf(lg4[0], lg4[1]), fmaxf(lg4[2], lg4[3]));
        const float e0 = expf(lg4[0] - mx), e1 = expf(lg4[1] - mx);
        const float e2 = expf(lg4[2] - mx), e3 = expf(lg4[3] - mx);
        gate_s[tid] = 0.25f * expf(lg4[tid] - mx) / ((e0 + e1) + (e2 + e3));
    }
    if (tid >= 128 && tid < 256) {
        const int t2 = tid - 128;
        const int cc = t2 >> 5, e = t2 & 31;
        const float invBF = 1.0f / ((float)B_DIM * (float)F_DIM);
        const float mu = ldsT[t2] * invBF;
        const float ey2 = ldsT[128 + t2] * invBF;
        inv_s[cc][e] = rsqrtf(ey2 - mu * mu + EPS_BN);
        mu_s[cc][e] = mu;
    }
    __syncthreads();

    for (int idx = tid; idx < 512; idx += 256) {
        const int kp = idx >> 5;
        const int e = idx & 31;
        const int i0 = kp * 2;
        float w0 = 0.f, w1 = 0.f;
#pragma unroll
        for (int cc = 0; cc < 4; ++cc) {
            const int d = 4 << cc;
            if (i0 < d) {
                const float* w = (cc == 0) ? w4 : (cc == 1) ? w8 : (cc == 2) ? w16 : w32;
                const float gi = gate_s[cc] * inv_s[cc][e];
                const size_t base = ((size_t)f * d + i0) * E_DIM + e;
                w0 = fmaf(gi, w[base], w0);
                w1 = fmaf(gi, w[base + E_DIM], w1);
            }
        }
        union { _Float16 h[2]; uint32_t uu; } ph, pl;
        const _Float16 h0 = (_Float16)w0, h1 = (_Float16)w1;
        ph.h[0] = h0; ph.h[1] = h1;
        pl.h[0] = (_Float16)(w0 - (float)h0);
        pl.h[1] = (_Float16)(w1 - (float)h1);
        ldsWhp[idx] = ph.uu;
        ldsWlp[idx] = pl.uu;
    }
    if (tid < E_DIM) {
        float a = 0.f;
#pragma unroll
        for (int cc = 0; cc < 4; ++cc)
            a = fmaf(gate_s[cc], inv_s[cc][tid] * mu_s[cc][tid], a);
        ldsBias[tid] = a;
    }
    __syncthreads();

    // ---- apply main loop ----
    H8 wh[2], wl[2];
#pragma unroll
    for (int q = 0; q < 2; ++q)
#pragma unroll
        for (int pp = 0; pp < 4; ++pp) {
            const int kp = 8 * q + 4 * g + pp;
            wh[q].u[pp] = ldsWhp[kp * 32 + c];
            wl[q].u[pp] = ldsWlp[kp * 32 + c];
        }
    const float be = ldsBias[c];

    const int wbase = blockIdx.x * A_RPB + wave * (A_RPB / 4);
#pragma unroll
    for (int t = 0; t < (A_RPB / 4) / 32; ++t) {
        const int b0 = wbase + t * 32;
        const float4* pa = reinterpret_cast<const float4*>(
            emb + (size_t)(b0 + c) * ROWSTRIDE + f * E_DIM + 8 * g);
        f32x16 acc;
#pragma unroll
        for (int i = 0; i < 16; ++i) acc[i] = 0.f;
#pragma unroll
        for (int q = 0; q < 2; ++q) {
            const float4 v0 = pa[4 * q];
            const float4 v1 = pa[4 * q + 1];
            const float x[8] = {v0.x, v0.y, v0.z, v0.w, v1.x, v1.y, v1.z, v1.w};
            H8 ah, al;
#pragma unroll
            for (int e = 0; e < 8; ++e) {
                const _Float16 hh = (_Float16)x[e];
                ah.h[e] = hh;
                al.h[e] = (_Float16)(x[e] - (float)hh);
            }
            acc = __builtin_amdgcn_mfma_f32_32x32x16_f16(ah.v, wh[q].v, acc, 0, 0, 0);
            acc = __builtin_amdgcn_mfma_f32_32x32x16_f16(ah.v, wl[q].v, acc, 0, 0, 0);
            acc = __builtin_amdgcn_mfma_f32_32x32x16_f16(al.v, wh[q].v, acc, 0, 0, 0);
        }
        float* po = out + (size_t)b0 * ROWSTRIDE + f * E_DIM + c;
#pragma unroll
        for (int r = 0; r < 16; ++r) {
            const int mrow = (r & 3) + 8 * (r >> 2) + 4 * g;
            __builtin_nontemporal_store(acc[r] - be, po + (size_t)mrow * ROWSTRIDE);
        }
    }
}

extern "C" void kernel_launch(void* const* d_in, const int* in_sizes, int n_in,
                              void* d_out, int out_size, void* d_ws, size_t ws_size,
                              hipStream_t stream) {
    const float* emb   = (const float*)d_in[0];
    const float* w4    = (const float*)d_in[1];
    const float* w8    = (const float*)d_in[2];
    const float* w16   = (const float*)d_in[3];
    const float* w32   = (const float*)d_in[4];
    const float* gate  = (const float*)d_in[5];
    const float* noise = (const float*)d_in[6];
    float* out = (float*)d_out;

    float* m12f = (float*)d_ws;       // NREP*256 floats

    hipMemsetAsync(m12f, 0, NREP * 256 * sizeof(float), stream);
    k_stats<<<dim3(S_CHUNKS, F_DIM), 256, 0, stream>>>(emb, w4, w8, w16, w32, m12f);
    k_apply<<<dim3(A_CHUNKS, F_DIM), 256, 0, stream>>>(emb, m12f, gate, noise,
                                                       w4, w8, w16, w32, out);
}